// Round 1
// 152.735 us; speedup vs baseline: 1.0342x; 1.0342x over previous
//
#include <hip/hip_runtime.h>
#include <stdint.h>

#pragma clang fp contract(off)

#define NCELL 49
#define NCLS  20
#define NSEG  16
#define SPLIT 14   // cand rows: role A computes i<SPLIT, role B computes SPLIT..48

struct Box { float x1, y1, x2, y2; };

// Bit-exact branchless sigmoid (see R9 note).
__device__ __forceinline__ float sigmoid_ref(float x) {
#pragma clang fp contract(off)
  float z = expf(-fabsf(x));
  float num = (x >= 0.0f) ? 1.0f : z;
  return num / (1.0f + z);
}

// Exact IoU (IEEE divide) — used only where the VALUE feeds comparisons that
// must match the reference bit-for-bit (GT match v>mx chain, mx>0.5).
__device__ __forceinline__ float iou_box(Box a, Box b) {
#pragma clang fp contract(off)
  float lx = fmaxf(a.x1, b.x1);
  float ly = fmaxf(a.y1, b.y1);
  float rx = fminf(a.x2, b.x2);
  float ry = fminf(a.y2, b.y2);
  float w = fmaxf(rx - lx, 0.0f);
  float h = fmaxf(ry - ly, 0.0f);
  float inter = w * h;
  float aa = (a.x2 - a.x1) * (a.y2 - a.y1);
  float ab = (b.x2 - b.x1) * (b.y2 - b.y1);
  return inter / (aa + ab - inter);
}

// R11: (iou > 0.5) without the divide. inter > 0.5*union  <=>
// fl(inter/union) > 0.5 except when the real quotient lies in
// (0.5, 0.5*(1+2^-24)] — one-sided 3e-8 relative window; expected flips
// over all NMS comparisons in this bench ~1e-5. 0.5*u is exact.
__device__ __forceinline__ bool iou_gt_half(Box a, Box b) {
#pragma clang fp contract(off)
  float lx = fmaxf(a.x1, b.x1);
  float ly = fmaxf(a.y1, b.y1);
  float rx = fminf(a.x2, b.x2);
  float ry = fminf(a.y2, b.y2);
  float w = fmaxf(rx - lx, 0.0f);
  float h = fmaxf(ry - ly, 0.0f);
  float inter = w * h;
  float aa = (a.x2 - a.x1) * (a.y2 - a.y1);
  float ab = (b.x2 - b.x1) * (b.y2 - b.y1);
  float u = aa + ab - inter;
  return inter > 0.5f * u;
}

__device__ __forceinline__ unsigned mbcnt64(unsigned long long m) {
  return __builtin_amdgcn_mbcnt_hi((unsigned)(m >> 32),
         __builtin_amdgcn_mbcnt_lo((unsigned)m, 0u));
}
#define WSYNC() __builtin_amdgcn_wave_barrier()

// 512 threads = 8 waves = 4 images x 2 roles. Role A (waves 0-3): pred
// decode + rank + cand-low + early-resolve + resolve + TP + stats/store.
// Role B (waves 4-7): GT decode + compacted GT-match + cand-high.
// R11 changes vs R10 (math identical; absmax 0.0 expected):
//  * NMS cand tests use iou_gt_half (no divide)         [~1e-5 flip risk]
//  * GT match iterates a ballot-compacted valid-GT list  [exact]
//  * cand split 19 -> SPLIT=14; candHi is 64-bit         [exact]
//  * resolve iterations i<SPLIT run pre-sync2 (candLo-only dependence) [exact]
//  * per-class stats via LDS histograms instead of 20-ballot loops     [exact]
__global__ __launch_bounds__(512) void k_per_image(
    const float* __restrict__ target, const float* __restrict__ output,
    uint8_t* __restrict__ entries, int* __restrict__ gt_count,
    unsigned* __restrict__ totals, int batch, int segimg)
{
#pragma clang fp contract(off)
  __shared__ float4   pbox[4][64];
  __shared__ int2     pcc [4][64];
  __shared__ float4   gboxC[4][64];          // compacted valid GTs (prefix ngt)
  __shared__ int      gcvC [4][64];          // cls | (orig g << 8); 255 sentinel
  __shared__ float    ctab[4][64];
  __shared__ float2   mtab[4][64];
  __shared__ unsigned long long candHi[4][64];
  __shared__ unsigned phist[4][NCLS];
  __shared__ unsigned ghist[4][NCLS];

  int tid = threadIdx.x;
  int lane = tid & 63;
  int w = tid >> 6;
  int m = w & 3;                 // image slot in block
  int roleB = w >> 2;            // 0 = A (pred side), 1 = B (GT side)
  int img = blockIdx.x * 4 + m;
  bool act = img < batch;        // wave-uniform
  bool a = act && (lane < NCELL);

  int ngt = 0;                   // B-side register (live across sync1)

  if (act) {
    if (roleB == 0) {
      // ---------------- role A: predictions ----------------
      if (lane < NCLS) phist[m][lane] = 0u;
      float ov[30];
      if (a) {
        const float2* O2 = (const float2*)(output + (size_t)img * 1470 + lane * 30);
#pragma unroll
        for (int i = 0; i < 15; ++i) { float2 o = O2[i]; ov[2*i] = o.x; ov[2*i+1] = o.y; }
      } else {
#pragma unroll
        for (int i = 0; i < 30; ++i) ov[i] = 0.0f;
      }
      float fjx = (float)(lane % 7), fiy = (float)(lane / 7);
      float myc = -1.0f; int myk = 0; float px1 = 0, py1 = 0, px2 = 0, py2 = 0;
      if (a) {
        float s0 = sigmoid_ref(ov[4]);
        float s1 = sigmoid_ref(ov[9]);
        myc = fmaxf(s0, s1);
        int resp = (s1 > s0) ? 1 : 0;    // first max wins (sigmoid monotone)
        float x  = sigmoid_ref(ov[resp * 5 + 0]);
        float y  = sigmoid_ref(ov[resp * 5 + 1]);
        float ww = sigmoid_ref(ov[resp * 5 + 2]);
        float hh = sigmoid_ref(ov[resp * 5 + 3]);
        float obv = sigmoid_ref(ov[10]); myk = 0;
#pragma unroll
        for (int c = 1; c < NCLS; ++c) {
          float v = sigmoid_ref(ov[10 + c]);
          if (v > obv) { obv = v; myk = c; }
        }
        float cx = (x + fjx) * 64.0f, cy = (y + fiy) * 64.0f;
        float W = ww * 448.0f, H = hh * 448.0f;
        px1 = cx - W * 0.5f; py1 = cy - H * 0.5f;
        px2 = cx + W * 0.5f; py2 = cy + H * 0.5f;
      }
      ctab[m][lane] = myc;
      WSYNC();
      // stable rank (argsort(-conf), index tiebreak)
      int r = 0;
#pragma unroll
      for (int j = 0; j < NCELL; ++j) {
        float cj = ctab[m][j];
        r += (cj > myc) || (cj == myc && j < lane);
      }
      r = a ? r : lane;
      pbox[m][r] = make_float4(px1, py1, px2, py2);
      pcc[m][r]  = make_int2(myk, __float_as_int(myc));
    } else {
      // ---------------- role B: ground truth ----------------
      if (lane < NCLS) ghist[m][lane] = 0u;
      // sentinel-init compacted arrays (slots >= ngt read by unroll-4 tail)
      gboxC[m][lane] = make_float4(0.0f, 0.0f, 0.0f, 0.0f);
      gcvC[m][lane]  = 255;          // class 255: never matches scls 0..19
      WSYNC();
      float tv[30];
      if (a) {
        const float2* T2 = (const float2*)(target + (size_t)img * 1470 + lane * 30);
#pragma unroll
        for (int i = 0; i < 15; ++i) { float2 t = T2[i]; tv[2*i] = t.x; tv[2*i+1] = t.y; }
      } else {
#pragma unroll
        for (int i = 0; i < 30; ++i) tv[i] = 0.0f;
      }
      float fjx = (float)(lane % 7), fiy = (float)(lane / 7);
      int gcls = 0;
      float tbv = tv[10];
#pragma unroll
      for (int c = 1; c < NCLS; ++c) { float v = tv[10 + c]; if (v > tbv) { tbv = v; gcls = c; } }
      bool gval = a && (tv[4] > 0.5f);
      float cx = (tv[0] + fjx) * 64.0f, cy = (tv[1] + fiy) * 64.0f;
      float w2 = tv[2] * 448.0f, h2 = tv[3] * 448.0f;
      // order-preserving compaction of valid GTs (exact: excluded g never
      // updated mx in R10 either; included g keep ascending order)
      unsigned long long gm = __ballot(gval);
      ngt = (int)__popcll(gm);
      if (gval) {
        int pos = (int)mbcnt64(gm);
        gboxC[m][pos] = make_float4(cx - w2 * 0.5f, cy - h2 * 0.5f,
                                    cx + w2 * 0.5f, cy + h2 * 0.5f);
        gcvC[m][pos]  = gcls | (lane << 8);
        atomicAdd(&ghist[m][gcls], 1u);
      }
    }
  }

  __syncthreads();   // sync1: pbox/pcc + gboxC/gcvC visible block-wide

  float4 sb4; int2 cc; Box myS; int scls = 0; float sconf = -1.0f;
  unsigned long long candLo = 0, sup = 0;
  if (act) {
    sb4 = pbox[m][lane];
    cc  = pcc[m][lane];
    myS.x1 = sb4.x; myS.y1 = sb4.y; myS.x2 = sb4.z; myS.y2 = sb4.w;
    scls = cc.x; sconf = __int_as_float(cc.y);

    if (roleB == 0) {
      // cand low half: i = 0..SPLIT-1 (divide-free test)
#pragma unroll
      for (int i = 0; i < SPLIT; ++i) {
        float4 b4 = pbox[m][i];
        int ki = pcc[m][i].x;
        Box bi; bi.x1 = b4.x; bi.y1 = b4.y; bi.x2 = b4.z; bi.y2 = b4.w;
        bool s = a && (lane > i) && (scls == ki) && iou_gt_half(myS, bi);
        candLo |= s ? (1ull << i) : 0ull;
      }
      // early resolve: iterations i<SPLIT only touch candmask bits <SPLIT,
      // which are exactly candLo — run them before sync2 (overlaps role B).
#pragma unroll
      for (int i = 0; i < SPLIT; ++i) {
        unsigned long long bi = __ballot(((candLo >> i) & 1ull) != 0ull);
        bool keep = ((sup >> i) & 1ull) == 0ull;
        sup |= keep ? bi : 0ull;
      }
    } else {
      // GT match over compacted list (identical first-max semantics),
      // unroll-4 blocks keep 4 independent LDS reads + IoU chains in flight.
      float mx = -1.0f; int best = 0;
      for (int g0 = 0; g0 < ngt; g0 += 4) {
#pragma unroll
        for (int k = 0; k < 4; ++k) {
          int g = g0 + k;                       // slots < 52 < 64: in-bounds
          float4 b4 = gboxC[m][g];
          int cv = gcvC[m][g];
          Box bg; bg.x1 = b4.x; bg.y1 = b4.y; bg.x2 = b4.z; bg.y2 = b4.w;
          float v = iou_box(myS, bg);           // exact divide (value feeds v>mx)
          bool upd = a && (g < ngt) && (scls == (cv & 255)) && (v > mx);
          mx = upd ? v : mx;
          best = upd ? (cv >> 8) : best;
        }
      }
      mtab[m][lane] = make_float2(mx, __int_as_float(best));
      // cand high half: i = SPLIT..48 -> bit (i-SPLIT) (divide-free test)
      unsigned long long ch = 0;
#pragma unroll
      for (int i = SPLIT; i < NCELL; ++i) {
        float4 b4 = pbox[m][i];
        int ki = pcc[m][i].x;
        Box bi; bi.x1 = b4.x; bi.y1 = b4.y; bi.x2 = b4.z; bi.y2 = b4.w;
        bool s = a && (lane > i) && (scls == ki) && iou_gt_half(myS, bi);
        ch |= s ? (1ull << (i - SPLIT)) : 0ull;
      }
      candHi[m][lane] = ch;
    }
  }

  __syncthreads();   // sync2: mtab + candHi visible

  if (act) {
    if (roleB == 0) {
      unsigned long long candmask =
          candLo | (candHi[m][lane] << SPLIT);

      // NMS serial resolve, remaining iterations (continues early `sup`)
#pragma unroll
      for (int i = SPLIT; i < NCELL; ++i) {
        unsigned long long bi = __ballot(((candmask >> i) & 1ull) != 0ull);
        bool keep = ((sup >> i) & 1ull) == 0ull;
        sup |= keep ? bi : 0ull;
      }
      bool vp = a && !((sup >> lane) & 1ull) && (sconf > 0.5f);

      // greedy TP assignment (reads B's mtab)
      unsigned long long vpmask = __ballot(vp);
      unsigned long long matched = 0, hits = 0;
#pragma unroll 7
      for (int i = 0; i < NCELL; ++i) {
        float2 f2 = mtab[m][i];
        float mxi = f2.x;
        int bi = __float_as_int(f2.y);
        bool hit = ((vpmask >> i) & 1ull) && (mxi > 0.5f) && !((matched >> bi) & 1ull);
        matched |= hit ? (1ull << bi) : 0ull;
        hits    |= hit ? (1ull << i)  : 0ull;
      }

      if (a) {
        entries[(size_t)img * NCELL + lane] =
            (uint8_t)(scls | (vp ? 32 : 0) | (((hits >> lane) & 1ull) ? 64 : 0));
      }

      // totals stats (valid,tp) per (segment,class) via LDS histogram
      int seg = img / segimg;
      if (a) {
        unsigned add = (vp ? 0x10000u : 0u) |
                       ((((hits >> lane) & 1ull) != 0ull) ? 1u : 0u);
        if (add) atomicAdd(&phist[m][scls], add);
      }
      WSYNC();   // same-wave LDS in-order; fence compiler reordering
      if (lane < NCLS) {
        unsigned pkt = phist[m][lane];
        if (pkt) atomicAdd(&totals[seg * 32 + lane], pkt);
      }
    } else {
      // gt_count stats from B's pre-sync1 LDS histogram
      if (lane < NCLS) {
        unsigned g = ghist[m][lane];
        if (g) atomicAdd(&gt_count[lane], (int)g);
      }
    }
  }
}

__device__ __forceinline__ unsigned match_mask(unsigned w, unsigned wantx4) {
  unsigned y = (w & 0x3f3f3f3fu) ^ wantx4;
  return ~(y + 0x7f7f7f7fu) & 0x80808080u;
}

__device__ __forceinline__ uint4 load_tile(const uint8_t* entries, int e, int e1, int ne) {
  uint4 w4 = make_uint4(0, 0, 0, 0);
  if (e < e1) {
    int p = e << 4;
    if (p + 16 <= ne) {
      w4 = *(const uint4*)(entries + p);
    } else {
      unsigned ws[4] = {0, 0, 0, 0};
      for (int k = 0; k < ne - p; ++k)
        ws[k >> 2] |= ((unsigned)entries[p + k]) << (8 * (k & 3));
      w4.x = ws[0]; w4.y = ws[1]; w4.z = ws[2]; w4.w = ws[3];
    }
  }
  return w4;
}

// R10's apB (NSEG=16; best-measured tail) + lane-parallel totals prefix.
__global__ __launch_bounds__(256) void k_apB(
    const uint8_t* __restrict__ entries, const unsigned* __restrict__ totals,
    const int* __restrict__ gt_count, double* __restrict__ partials,
    unsigned* __restrict__ counter, float* __restrict__ out,
    int ne, int segimg)
{
#pragma clang fp contract(off)
  int c = blockIdx.x / NSEG, s = blockIdx.x % NSEG;
  int tid = threadIdx.x, wid = tid >> 6, lane = tid & 63;
  float g2 = (float)gt_count[c] + 1e-6f;
  unsigned wantx4 = (32u + (unsigned)c) * 0x01010101u;

  int nel = (ne + 15) >> 4;
  int segel = segimg * NCELL / 16;
  int se0 = s * segel; if (se0 > nel) se0 = nel;
  int se1 = se0 + segel; if (se1 > nel) se1 = nel;
  int elw = (se1 > se0) ? ((se1 - se0 + 3) >> 2) : 0;
  int e0 = se0 + wid * elw; if (e0 > se1) e0 = se1;
  int e1 = e0 + elw; if (e1 > se1) e1 = se1;
  int ntile = (e1 > e0) ? ((e1 - e0 + 63) >> 6) : 0;

  // global prefix: lane-parallel load + wave reduce (exact ints)
  unsigned long long pk = 0;
  if (lane < s) {
    unsigned t2 = totals[lane * 32 + c];
    pk = ((unsigned long long)(t2 >> 16) << 32) | (unsigned long long)(t2 & 0xffffu);
  }
#pragma unroll
  for (int d = 1; d < 64; d <<= 1) pk += __shfl_xor(pk, d, 64);
  unsigned Jrun = (unsigned)(pk >> 32), Trun = (unsigned)(pk & 0xffffffffull);

  unsigned mv = 0, mt = 0;
  for (int t = 0; t < ntile; ++t) {
    uint4 w4 = load_tile(entries, e0 + t * 64 + lane, e1, ne);
    unsigned wsv[4] = {w4.x, w4.y, w4.z, w4.w};
#pragma unroll
    for (int q = 0; q < 4; ++q) {
      unsigned m = match_mask(wsv[q], wantx4);
      mv += __popc(m);
      mt += __popc(m & (wsv[q] << 1));
    }
  }
  unsigned long long tot = ((unsigned long long)mv << 32) | (unsigned long long)mt;
#pragma unroll
  for (int d = 1; d < 64; d <<= 1) tot += __shfl_xor(tot, d, 64);
  __shared__ unsigned long long wt[4];
  __shared__ double wacc[4];
  __shared__ int islast;
  __shared__ float apf_s[NCLS];
  if (lane == 0) wt[wid] = tot;
  __syncthreads();
  for (int w2 = 0; w2 < wid; ++w2) {
    Jrun += (unsigned)(wt[w2] >> 32);
    Trun += (unsigned)(wt[w2] & 0xffffffffull);
  }

  double acc = 0.0;
  for (int t = 0; t < ntile; ++t) {
    int e = e0 + t * 64 + lane;
    int p = e << 4;
    uint4 w4 = load_tile(entries, e, e1, ne);
    unsigned wsv[4] = {w4.x, w4.y, w4.z, w4.w};
    unsigned mm[4], tm[4];
    unsigned cv = 0, ct = 0;
#pragma unroll
    for (int q = 0; q < 4; ++q) {
      unsigned m = match_mask(wsv[q], wantx4);
      mm[q] = m; tm[q] = m & (wsv[q] << 1);
      cv += __popc(m); ct += __popc(tm[q]);
    }
    unsigned jexcl = 0, texcl = 0, jtt = 0, ttt = 0;
#pragma unroll
    for (int b = 0; b < 5; ++b) {
      unsigned long long mj = __ballot(((cv >> b) & 1u) != 0u);
      unsigned long long mk = __ballot(((ct >> b) & 1u) != 0u);
      jexcl += mbcnt64(mj) << b;
      texcl += mbcnt64(mk) << b;
      jtt   += (unsigned)__popcll(mj) << b;
      ttt   += (unsigned)__popcll(mk) << b;
    }
    unsigned jr = Jrun + jexcl;
    unsigned tr = Trun + texcl;
#pragma unroll
    for (int q = 0; q < 4; ++q) {
      unsigned m = mm[q];
      while (m) {
        unsigned bit = (unsigned)__builtin_ctz(m);
        m &= m - 1;
        ++jr;
        if (tm[q] & (1u << bit)) {
          ++tr;
          int pos = p + 4 * q + (int)(bit >> 3);
          float ft = (float)tr, fj = (float)jr;
          float r_cur  = ft / g2;
          float r_prev = (ft - 1.0f) / g2;
          float p_cur  = ft / (fj + 1e-6f);
          float p_prev = (pos == 0) ? 1.0f
                                    : (ft - 1.0f) / ((fj - 1.0f) + 1e-6f);
          acc += (double)((r_cur - r_prev) * (p_cur + p_prev) * 0.5f);
        }
      }
    }
    Jrun += jtt;
    Trun += ttt;
  }

  for (int d = 32; d > 0; d >>= 1) acc += __shfl_down(acc, d, 64);
  if (lane == 0) wacc[wid] = acc;
  __syncthreads();
  if (tid == 0) {
    double bp = wacc[0] + wacc[1] + wacc[2] + wacc[3];
    __hip_atomic_store(&partials[blockIdx.x], bp,
                       __ATOMIC_RELEASE, __HIP_MEMORY_SCOPE_AGENT);
    unsigned prev = __hip_atomic_fetch_add(counter, 1u,
                       __ATOMIC_ACQ_REL, __HIP_MEMORY_SCOPE_AGENT);
    islast = (prev == (unsigned)(NCLS * NSEG - 1)) ? 1 : 0;
  }
  __syncthreads();
  if (islast) {
    if (tid < NCLS) {
      double d2 = 0.0;
#pragma unroll
      for (int s2 = 0; s2 < NSEG; ++s2)
        d2 += __hip_atomic_load(&partials[tid * NSEG + s2],
                                __ATOMIC_ACQUIRE, __HIP_MEMORY_SCOPE_AGENT);
      apf_s[tid] = (float)d2;
    }
    __syncthreads();
    if (tid == 0) {
      float sf = 0.0f, nf = 0.0f;
      for (int cc = 0; cc < NCLS; ++cc)
        if (gt_count[cc] > 0) { sf += apf_s[cc]; nf += 1.0f; }
      out[0] = sf / fmaxf(nf, 1.0f);
    }
  }
}

extern "C" void kernel_launch(void* const* d_in, const int* in_sizes, int n_in,
                              void* d_out, int out_size, void* d_ws, size_t ws_size,
                              hipStream_t stream) {
  const float* target = (const float*)d_in[0];
  const float* output = (const float*)d_in[1];
  int batch = in_sizes[0] / (NCELL * 30);
  int ne = batch * NCELL;
  int segimg = (((batch + NSEG - 1) / NSEG) + 15) & ~15;  // 16-image aligned

  uint8_t*  entries  = (uint8_t*)d_ws;
  size_t offA = ((size_t)ne + 255) & ~(size_t)255;
  int*      gt_count = (int*)((char*)d_ws + offA);                 // 256 B
  unsigned* totals   = (unsigned*)((char*)d_ws + offA + 256);      // 2048 B
  unsigned* counter  = (unsigned*)((char*)d_ws + offA + 256 + 2048);
  double*   partials = (double*)((char*)d_ws + offA + 4096);       // 2560 B

  (void)hipMemsetAsync((char*)d_ws + offA, 0, 4096, stream);
  k_per_image<<<(batch + 3) / 4, 512, 0, stream>>>(
      target, output, entries, gt_count, totals, batch, segimg);
  k_apB<<<NCLS * NSEG, 256, 0, stream>>>(
      entries, totals, gt_count, partials, counter, (float*)d_out, ne, segimg);
}

// Round 2
// 145.678 us; speedup vs baseline: 1.0843x; 1.0484x over previous
//
#include <hip/hip_runtime.h>
#include <stdint.h>

#pragma clang fp contract(off)

#define NCELL 49
#define NCLS  20
#define NSEG  16
#define SPLIT 36   // cand rows: role A (fused resolve) i<SPLIT, role B SPLIT..48

struct Box { float x1, y1, x2, y2; };

// Bit-exact branchless sigmoid (see R9 note).
__device__ __forceinline__ float sigmoid_ref(float x) {
#pragma clang fp contract(off)
  float z = expf(-fabsf(x));
  float num = (x >= 0.0f) ? 1.0f : z;
  return num / (1.0f + z);
}

// Exact IoU (IEEE divide) — value feeds reference-visible comparisons.
__device__ __forceinline__ float iou_box(Box a, Box b) {
#pragma clang fp contract(off)
  float lx = fmaxf(a.x1, b.x1);
  float ly = fmaxf(a.y1, b.y1);
  float rx = fminf(a.x2, b.x2);
  float ry = fminf(a.y2, b.y2);
  float w = fmaxf(rx - lx, 0.0f);
  float h = fmaxf(ry - ly, 0.0f);
  float inter = w * h;
  float aa = (a.x2 - a.x1) * (a.y2 - a.y1);
  float ab = (b.x2 - b.x1) * (b.y2 - b.y1);
  return inter / (aa + ab - inter);
}

// (iou > 0.5) without the divide (R11; ~3e-8 one-sided window).
__device__ __forceinline__ bool iou_gt_half(Box a, Box b) {
#pragma clang fp contract(off)
  float lx = fmaxf(a.x1, b.x1);
  float ly = fmaxf(a.y1, b.y1);
  float rx = fminf(a.x2, b.x2);
  float ry = fminf(a.y2, b.y2);
  float w = fmaxf(rx - lx, 0.0f);
  float h = fmaxf(ry - ly, 0.0f);
  float inter = w * h;
  float aa = (a.x2 - a.x1) * (a.y2 - a.y1);
  float ab = (b.x2 - b.x1) * (b.y2 - b.y1);
  float u = aa + ab - inter;
  return inter > 0.5f * u;
}

__device__ __forceinline__ unsigned mbcnt64(unsigned long long m) {
  return __builtin_amdgcn_mbcnt_hi((unsigned)(m >> 32),
         __builtin_amdgcn_mbcnt_lo((unsigned)m, 0u));
}
#define WSYNC() __builtin_amdgcn_wave_barrier()

// R12: 128 threads = 2 waves = 1 image. Wave 0 (A): pred decode (raw-argmax
// fast path, 5 sigmoids) + rank + fused cand/resolve rows 0..35 + late
// resolve + claim-table TP + stats. Wave 1 (B): GT decode + compacted
// GT-match + cand rows 36..48 + gt_count.
// Exactness: raw-x argmax == sigmoid argmax except on rounding plateaus;
// conservative slack 4e-6*e^x (>= plateau width ~2.4e-6*e^x) triggers the
// full-sigmoid reference fallback. Claim-table TP == serial greedy (first
// eligible claimant of a GT always wins; later ones always blocked).
__global__ __launch_bounds__(128) void k_per_image(
    const float* __restrict__ target, const float* __restrict__ output,
    uint8_t* __restrict__ entries, int* __restrict__ gt_count,
    unsigned* __restrict__ totals, int batch, int segimg)
{
#pragma clang fp contract(off)
  __shared__ float4   pbox[64];
  __shared__ int2     pcc [64];
  __shared__ float4   gboxC[64];          // compacted valid GTs (prefix ngt)
  __shared__ int      gcvC [64];          // cls | (orig g << 8); 255 sentinel
  __shared__ float    ctab[64];
  __shared__ float2   mtab[64];
  __shared__ unsigned candHi[64];         // bits for rows SPLIT..48
  __shared__ int      claim[64];          // first-claimant lane per GT
  __shared__ unsigned phist[NCLS];
  __shared__ unsigned ghist[NCLS];

  int tid = threadIdx.x;
  int lane = tid & 63;
  int roleB = tid >> 6;            // 0 = A (pred side), 1 = B (GT side)
  int img = blockIdx.x;
  bool a = (lane < NCELL);

  int ngt = 0;                     // B-side register (live across sync1)

  if (roleB == 0) {
    // ---------------- role A: predictions ----------------
    if (lane < NCLS) phist[lane] = 0u;
    claim[lane] = 64;
    float ov[30];
    if (a) {
      const float2* O2 = (const float2*)(output + (size_t)img * 1470 + lane * 30);
#pragma unroll
      for (int i = 0; i < 15; ++i) { float2 o = O2[i]; ov[2*i] = o.x; ov[2*i+1] = o.y; }
    } else {
#pragma unroll
      for (int i = 0; i < 30; ++i) ov[i] = 0.0f;
    }
    float fjx = (float)(lane % 7), fiy = (float)(lane / 7);
    float myc = -1.0f; int myk = 0; float px1 = 0, py1 = 0, px2 = 0, py2 = 0;
    if (a) {
      float x4 = ov[4], x9 = ov[9];
      float xm = fmaxf(x4, x9);
      // raw-domain class argmax with runner-up tracking
      float xc = ov[10], xr = -3.0e38f; int kk = 0;
#pragma unroll
      for (int c = 1; c < NCLS; ++c) {
        float v = ov[10 + c];
        bool gt = v > xc;
        float nr = gt ? xc : fmaxf(xr, v);
        kk = gt ? c : kk;
        xc = gt ? v : xc;
        xr = nr;
      }
      // conservative sigmoid-plateau slack: width <= ~2.4e-6*e^x
      bool slowK = (xc - xr) < fmaxf(1e-5f, 4e-6f * exp2f(xc * 1.44269504f));
      bool slowR = fabsf(x4 - x9) < fmaxf(1e-5f, 4e-6f * exp2f(xm * 1.44269504f));
      int resp = (x9 > x4) ? 1 : 0;
      myc = sigmoid_ref(xm);
      myk = kk;
      if (slowK || slowR) {          // rare: exact reference fallback
        float s0 = sigmoid_ref(x4);
        float s1 = sigmoid_ref(x9);
        myc = fmaxf(s0, s1);
        resp = (s1 > s0) ? 1 : 0;
        float obv = sigmoid_ref(ov[10]); myk = 0;
#pragma unroll
        for (int c = 1; c < NCLS; ++c) {
          float v = sigmoid_ref(ov[10 + c]);
          if (v > obv) { obv = v; myk = c; }
        }
      }
      float bx = resp ? ov[5] : ov[0];
      float by = resp ? ov[6] : ov[1];
      float bw = resp ? ov[7] : ov[2];
      float bh = resp ? ov[8] : ov[3];
      float x  = sigmoid_ref(bx);
      float y  = sigmoid_ref(by);
      float ww = sigmoid_ref(bw);
      float hh = sigmoid_ref(bh);
      float cx = (x + fjx) * 64.0f, cy = (y + fiy) * 64.0f;
      float W = ww * 448.0f, H = hh * 448.0f;
      px1 = cx - W * 0.5f; py1 = cy - H * 0.5f;
      px2 = cx + W * 0.5f; py2 = cy + H * 0.5f;
    }
    ctab[lane] = myc;
    WSYNC();
    // stable rank (argsort(-conf), index tiebreak)
    int r = 0;
#pragma unroll
    for (int j = 0; j < NCELL; ++j) {
      float cj = ctab[j];
      r += (cj > myc) || (cj == myc && j < lane);
    }
    r = a ? r : lane;
    pbox[r] = make_float4(px1, py1, px2, py2);
    pcc[r]  = make_int2(myk, __float_as_int(myc));
  } else {
    // ---------------- role B: ground truth ----------------
    if (lane < NCLS) ghist[lane] = 0u;
    gboxC[lane] = make_float4(0.0f, 0.0f, 0.0f, 0.0f);
    gcvC[lane]  = 255;
    WSYNC();
    float tv[30];
    if (a) {
      const float2* T2 = (const float2*)(target + (size_t)img * 1470 + lane * 30);
#pragma unroll
      for (int i = 0; i < 15; ++i) { float2 t = T2[i]; tv[2*i] = t.x; tv[2*i+1] = t.y; }
    } else {
#pragma unroll
      for (int i = 0; i < 30; ++i) tv[i] = 0.0f;
    }
    float fjx = (float)(lane % 7), fiy = (float)(lane / 7);
    int gcls = 0;
    float tbv = tv[10];
#pragma unroll
    for (int c = 1; c < NCLS; ++c) { float v = tv[10 + c]; if (v > tbv) { tbv = v; gcls = c; } }
    bool gval = a && (tv[4] > 0.5f);
    float cx = (tv[0] + fjx) * 64.0f, cy = (tv[1] + fiy) * 64.0f;
    float w2 = tv[2] * 448.0f, h2 = tv[3] * 448.0f;
    unsigned long long gm = __ballot(gval);
    ngt = (int)__popcll(gm);
    if (gval) {
      int pos = (int)mbcnt64(gm);
      gboxC[pos] = make_float4(cx - w2 * 0.5f, cy - h2 * 0.5f,
                               cx + w2 * 0.5f, cy + h2 * 0.5f);
      gcvC[pos]  = gcls | (lane << 8);
      atomicAdd(&ghist[gcls], 1u);
    }
  }

  __syncthreads();   // sync1: pbox/pcc + gboxC/gcvC visible

  float4 sb4 = pbox[lane];
  int2 cc = pcc[lane];
  Box myS; myS.x1 = sb4.x; myS.y1 = sb4.y; myS.x2 = sb4.z; myS.y2 = sb4.w;
  int scls = cc.x; float sconf = __int_as_float(cc.y);
  unsigned long long sup = 0;

  if (roleB == 0) {
    // fused cand + serial resolve, rows 0..SPLIT-1 (bit i consumed at iter i)
#pragma unroll 4
    for (int i = 0; i < SPLIT; ++i) {
      float4 b4 = pbox[i];
      int ki = pcc[i].x;
      Box bi; bi.x1 = b4.x; bi.y1 = b4.y; bi.x2 = b4.z; bi.y2 = b4.w;
      bool s = a && (lane > i) && (scls == ki) && iou_gt_half(myS, bi);
      unsigned long long bm = __ballot(s);
      bool keep = ((sup >> i) & 1ull) == 0ull;
      sup |= keep ? bm : 0ull;
    }
  } else {
    // GT match over compacted list (identical first-max semantics)
    float mx = -1.0f; int best = 0;
    for (int g0 = 0; g0 < ngt; g0 += 4) {
#pragma unroll
      for (int k2 = 0; k2 < 4; ++k2) {
        int g = g0 + k2;
        float4 b4 = gboxC[g];
        int cv = gcvC[g];
        Box bg; bg.x1 = b4.x; bg.y1 = b4.y; bg.x2 = b4.z; bg.y2 = b4.w;
        float v = iou_box(myS, bg);        // exact divide (value feeds v>mx)
        bool upd = a && (g < ngt) && (scls == (cv & 255)) && (v > mx);
        mx = upd ? v : mx;
        best = upd ? (cv >> 8) : best;
      }
    }
    mtab[lane] = make_float2(mx, __int_as_float(best));
    // cand rows SPLIT..48 -> bit (i-SPLIT)
    unsigned ch = 0;
#pragma unroll
    for (int i = SPLIT; i < NCELL; ++i) {
      float4 b4 = pbox[i];
      int ki = pcc[i].x;
      Box bi; bi.x1 = b4.x; bi.y1 = b4.y; bi.x2 = b4.z; bi.y2 = b4.w;
      bool s = a && (lane > i) && (scls == ki) && iou_gt_half(myS, bi);
      ch |= s ? (1u << (i - SPLIT)) : 0u;
    }
    candHi[lane] = ch;
    // gt_count stats (fire-and-forget, overlaps A's resolve)
    if (lane < NCLS) {
      unsigned g = ghist[lane];
      if (g) atomicAdd(&gt_count[lane], (int)g);
    }
  }

  __syncthreads();   // sync2: mtab + candHi visible

  if (roleB == 0) {
    unsigned chv = candHi[lane];
    // resolve remaining rows (continues early `sup`)
#pragma unroll
    for (int i = SPLIT; i < NCELL; ++i) {
      bool ci2 = ((chv >> (i - SPLIT)) & 1u) != 0u;
      unsigned long long bm = __ballot(ci2);
      bool keep = ((sup >> i) & 1ull) == 0ull;
      sup |= keep ? bm : 0ull;
    }
    bool vp = a && !((sup >> lane) & 1ull) && (sconf > 0.5f);

    // claim-table TP: first eligible claimant of each GT wins (== greedy)
    float2 f2 = mtab[lane];
    bool elig = vp && (f2.x > 0.5f);
    int best = __float_as_int(f2.y);
    if (elig) atomicMin(&claim[best], lane);
    WSYNC();
    bool hit = elig && (claim[best] == lane);

    if (a) {
      entries[(size_t)img * NCELL + lane] =
          (uint8_t)(scls | (vp ? 32 : 0) | (hit ? 64 : 0));
    }

    // totals stats (valid,tp) per (segment,class) via LDS histogram
    int seg = img / segimg;
    unsigned add = (vp ? 0x10000u : 0u) | (hit ? 1u : 0u);
    if (a && add) atomicAdd(&phist[scls], add);
    WSYNC();
    if (lane < NCLS) {
      unsigned pkt = phist[lane];
      if (pkt) atomicAdd(&totals[seg * 32 + lane], pkt);
    }
  }
}

__device__ __forceinline__ unsigned match_mask(unsigned w, unsigned wantx4) {
  unsigned y = (w & 0x3f3f3f3fu) ^ wantx4;
  return ~(y + 0x7f7f7f7fu) & 0x80808080u;
}

__device__ __forceinline__ uint4 load_tile(const uint8_t* entries, int e, int e1, int ne) {
  uint4 w4 = make_uint4(0, 0, 0, 0);
  if (e < e1) {
    int p = e << 4;
    if (p + 16 <= ne) {
      w4 = *(const uint4*)(entries + p);
    } else {
      unsigned ws[4] = {0, 0, 0, 0};
      for (int k = 0; k < ne - p; ++k)
        ws[k >> 2] |= ((unsigned)entries[p + k]) << (8 * (k & 3));
      w4.x = ws[0]; w4.y = ws[1]; w4.z = ws[2]; w4.w = ws[3];
    }
  }
  return w4;
}

// R10's apB (NSEG=16; best-measured tail) + lane-parallel totals prefix.
__global__ __launch_bounds__(256) void k_apB(
    const uint8_t* __restrict__ entries, const unsigned* __restrict__ totals,
    const int* __restrict__ gt_count, double* __restrict__ partials,
    unsigned* __restrict__ counter, float* __restrict__ out,
    int ne, int segimg)
{
#pragma clang fp contract(off)
  int c = blockIdx.x / NSEG, s = blockIdx.x % NSEG;
  int tid = threadIdx.x, wid = tid >> 6, lane = tid & 63;
  float g2 = (float)gt_count[c] + 1e-6f;
  unsigned wantx4 = (32u + (unsigned)c) * 0x01010101u;

  int nel = (ne + 15) >> 4;
  int segel = segimg * NCELL / 16;
  int se0 = s * segel; if (se0 > nel) se0 = nel;
  int se1 = se0 + segel; if (se1 > nel) se1 = nel;
  int elw = (se1 > se0) ? ((se1 - se0 + 3) >> 2) : 0;
  int e0 = se0 + wid * elw; if (e0 > se1) e0 = se1;
  int e1 = e0 + elw; if (e1 > se1) e1 = se1;
  int ntile = (e1 > e0) ? ((e1 - e0 + 63) >> 6) : 0;

  // global prefix: lane-parallel load + wave reduce (exact ints)
  unsigned long long pk = 0;
  if (lane < s) {
    unsigned t2 = totals[lane * 32 + c];
    pk = ((unsigned long long)(t2 >> 16) << 32) | (unsigned long long)(t2 & 0xffffu);
  }
#pragma unroll
  for (int d = 1; d < 64; d <<= 1) pk += __shfl_xor(pk, d, 64);
  unsigned Jrun = (unsigned)(pk >> 32), Trun = (unsigned)(pk & 0xffffffffull);

  unsigned mv = 0, mt = 0;
  for (int t = 0; t < ntile; ++t) {
    uint4 w4 = load_tile(entries, e0 + t * 64 + lane, e1, ne);
    unsigned wsv[4] = {w4.x, w4.y, w4.z, w4.w};
#pragma unroll
    for (int q = 0; q < 4; ++q) {
      unsigned m = match_mask(wsv[q], wantx4);
      mv += __popc(m);
      mt += __popc(m & (wsv[q] << 1));
    }
  }
  unsigned long long tot = ((unsigned long long)mv << 32) | (unsigned long long)mt;
#pragma unroll
  for (int d = 1; d < 64; d <<= 1) tot += __shfl_xor(tot, d, 64);
  __shared__ unsigned long long wt[4];
  __shared__ double wacc[4];
  __shared__ int islast;
  __shared__ float apf_s[NCLS];
  if (lane == 0) wt[wid] = tot;
  __syncthreads();
  for (int w2 = 0; w2 < wid; ++w2) {
    Jrun += (unsigned)(wt[w2] >> 32);
    Trun += (unsigned)(wt[w2] & 0xffffffffull);
  }

  double acc = 0.0;
  for (int t = 0; t < ntile; ++t) {
    int e = e0 + t * 64 + lane;
    int p = e << 4;
    uint4 w4 = load_tile(entries, e, e1, ne);
    unsigned wsv[4] = {w4.x, w4.y, w4.z, w4.w};
    unsigned mm[4], tm[4];
    unsigned cv = 0, ct = 0;
#pragma unroll
    for (int q = 0; q < 4; ++q) {
      unsigned m = match_mask(wsv[q], wantx4);
      mm[q] = m; tm[q] = m & (wsv[q] << 1);
      cv += __popc(m); ct += __popc(tm[q]);
    }
    unsigned jexcl = 0, texcl = 0, jtt = 0, ttt = 0;
#pragma unroll
    for (int b = 0; b < 5; ++b) {
      unsigned long long mj = __ballot(((cv >> b) & 1u) != 0u);
      unsigned long long mk = __ballot(((ct >> b) & 1u) != 0u);
      jexcl += mbcnt64(mj) << b;
      texcl += mbcnt64(mk) << b;
      jtt   += (unsigned)__popcll(mj) << b;
      ttt   += (unsigned)__popcll(mk) << b;
    }
    unsigned jr = Jrun + jexcl;
    unsigned tr = Trun + texcl;
#pragma unroll
    for (int q = 0; q < 4; ++q) {
      unsigned m = mm[q];
      while (m) {
        unsigned bit = (unsigned)__builtin_ctz(m);
        m &= m - 1;
        ++jr;
        if (tm[q] & (1u << bit)) {
          ++tr;
          int pos = p + 4 * q + (int)(bit >> 3);
          float ft = (float)tr, fj = (float)jr;
          float r_cur  = ft / g2;
          float r_prev = (ft - 1.0f) / g2;
          float p_cur  = ft / (fj + 1e-6f);
          float p_prev = (pos == 0) ? 1.0f
                                    : (ft - 1.0f) / ((fj - 1.0f) + 1e-6f);
          acc += (double)((r_cur - r_prev) * (p_cur + p_prev) * 0.5f);
        }
      }
    }
    Jrun += jtt;
    Trun += ttt;
  }

  for (int d = 32; d > 0; d >>= 1) acc += __shfl_down(acc, d, 64);
  if (lane == 0) wacc[wid] = acc;
  __syncthreads();
  if (tid == 0) {
    double bp = wacc[0] + wacc[1] + wacc[2] + wacc[3];
    __hip_atomic_store(&partials[blockIdx.x], bp,
                       __ATOMIC_RELEASE, __HIP_MEMORY_SCOPE_AGENT);
    unsigned prev = __hip_atomic_fetch_add(counter, 1u,
                       __ATOMIC_ACQ_REL, __HIP_MEMORY_SCOPE_AGENT);
    islast = (prev == (unsigned)(NCLS * NSEG - 1)) ? 1 : 0;
  }
  __syncthreads();
  if (islast) {
    if (tid < NCLS) {
      double d2 = 0.0;
#pragma unroll
      for (int s2 = 0; s2 < NSEG; ++s2)
        d2 += __hip_atomic_load(&partials[tid * NSEG + s2],
                                __ATOMIC_ACQUIRE, __HIP_MEMORY_SCOPE_AGENT);
      apf_s[tid] = (float)d2;
    }
    __syncthreads();
    if (tid == 0) {
      float sf = 0.0f, nf = 0.0f;
      for (int cc = 0; cc < NCLS; ++cc)
        if (gt_count[cc] > 0) { sf += apf_s[cc]; nf += 1.0f; }
      out[0] = sf / fmaxf(nf, 1.0f);
    }
  }
}

extern "C" void kernel_launch(void* const* d_in, const int* in_sizes, int n_in,
                              void* d_out, int out_size, void* d_ws, size_t ws_size,
                              hipStream_t stream) {
  const float* target = (const float*)d_in[0];
  const float* output = (const float*)d_in[1];
  int batch = in_sizes[0] / (NCELL * 30);
  int ne = batch * NCELL;
  int segimg = (((batch + NSEG - 1) / NSEG) + 15) & ~15;  // 16-image aligned

  uint8_t*  entries  = (uint8_t*)d_ws;
  size_t offA = ((size_t)ne + 255) & ~(size_t)255;
  int*      gt_count = (int*)((char*)d_ws + offA);                 // 256 B
  unsigned* totals   = (unsigned*)((char*)d_ws + offA + 256);      // 2048 B
  unsigned* counter  = (unsigned*)((char*)d_ws + offA + 256 + 2048);
  double*   partials = (double*)((char*)d_ws + offA + 4096);       // 2560 B

  (void)hipMemsetAsync((char*)d_ws + offA, 0, 4096, stream);
  k_per_image<<<batch, 128, 0, stream>>>(
      target, output, entries, gt_count, totals, batch, segimg);
  k_apB<<<NCLS * NSEG, 256, 0, stream>>>(
      entries, totals, gt_count, partials, counter, (float*)d_out, ne, segimg);
}